// Round 1
// 252.701 us; speedup vs baseline: 1.0288x; 1.0288x over previous
//
#include <hip/hip_runtime.h>
#include <hip/hip_bf16.h>
#include <cstddef>

#define BB 16
#define TT 4096
#define HH 512

typedef _Float16 half8 __attribute__((ext_vector_type(8)));
typedef float f32x4 __attribute__((ext_vector_type(4)));

__device__ __forceinline__ float fast_rcp(float x) { return __builtin_amdgcn_rcpf(x); }

// ---------------- prep ---------------------------------------------------------
// blocks 0..127 : pack Wv (f32 [n][k]) -> Bpack f16, layout [kb(16)][tn(32)][lane(64)][8]
//                 n = tn*16 + (lane&15), k = kb*32 + (lane>>4)*8 + j.
// blocks 128..191: qb[b][o] = query[b]·Wq[o] + bias[o] + conv_b[o]
// block  192     : zero ssum/ctx
__global__ void prep_kernel(const float* __restrict__ query,
                            const float* __restrict__ conv_b,
                            const float* __restrict__ Wq,
                            const float* __restrict__ Wv,
                            const float* __restrict__ bias,
                            _Float16* __restrict__ Bpack,
                            float* __restrict__ qb,
                            float* __restrict__ ssum,
                            float* __restrict__ ctx) {
    int blk = blockIdx.x;
    int tid = threadIdx.x;
    if (blk < 128) {
        int tn = blk >> 2, kq = blk & 3;
        int kb = kq * 4 + (tid >> 6);
        int lane = tid & 63;
        int n = tn * 16 + (lane & 15);
        int k = kb * 32 + ((lane >> 4) << 3);
        const float4* src = (const float4*)(Wv + (size_t)n * HH + k);
        float4 v0 = src[0], v1 = src[1];
        half8 h = { (_Float16)v0.x, (_Float16)v0.y, (_Float16)v0.z, (_Float16)v0.w,
                    (_Float16)v1.x, (_Float16)v1.y, (_Float16)v1.z, (_Float16)v1.w };
        *(half8*)(Bpack + ((size_t)(kb * 32 + tn) * 64 + lane) * 8) = h;
    } else if (blk < 192) {
        int q = blk - 128;
        int b = q >> 2, oq = q & 3;
        __shared__ float qrow[HH];
        for (int i = tid; i < HH; i += 256) qrow[i] = query[b * HH + i];
        __syncthreads();
        int wave = tid >> 6, lane = tid & 63;
        float4 q1 = *(const float4*)(qrow + lane * 8);
        float4 q2 = *(const float4*)(qrow + lane * 8 + 4);
        for (int i = wave; i < 128; i += 4) {
            int o = oq * 128 + i;
            const float4* w = (const float4*)(Wq + (size_t)o * HH);
            float4 a = w[lane * 2], c = w[lane * 2 + 1];
            float acc = a.x * q1.x + a.y * q1.y + a.z * q1.z + a.w * q1.w
                      + c.x * q2.x + c.y * q2.y + c.z * q2.z + c.w * q2.w;
            #pragma unroll
            for (int off = 1; off < 64; off <<= 1) acc += __shfl_xor(acc, off, 64);
            if (lane == 0) qb[b * HH + o] = acc + bias[o] + conv_b[o];
        }
    } else {
        for (int i = tid; i < BB; i += 256) ssum[i] = 0.f;
        for (int i = tid; i < BB * HH; i += 256) ctx[i] = 0.f;
    }
}

// ---------------- fused GEMM + conv + tanh + score + sigmoid + context ---------
// grid 1024 = 16 b x 64 t-tiles; block 512 thr = 8 waves; 2 blocks/CU (64 KiB
// dynamic LDS each) so one block's global->LDS stage overlaps the co-resident
// block's K-loop.  Block tile: 64 t x 512 o, K=512.  Wave ng: 64 rows x 32 cols
// (mt=4, nt=2); acc = 32 AGPR; B prefetch depth 2 via 4-slot register ring.
// __launch_bounds__(512,4) -> 128-reg budget (needed for 16 waves/CU).
// As staged once (xor-swizzled, dynamic LDS); K-loop barrier-free; tile reused
// for the fused context reduction.  last_attn halo staged to LDS; epilogue
// scalars (qb/conv_w/w_score) hoisted above the K-loop to hide their latency.
__global__ __launch_bounds__(512, 4) void gemm_fused_kernel(
        const float* __restrict__ value,
        const float* __restrict__ last_attn,
        const float* __restrict__ conv_w,
        const float* __restrict__ w_score,
        const float* __restrict__ b_score,
        const _Float16* __restrict__ Bpack,
        const float* __restrict__ qb,
        float* __restrict__ sbuf,
        float* __restrict__ ssum,
        float* __restrict__ ctx) {
    extern __shared__ _Float16 As[];    // 64 * 512 f16 = 64 KiB
    __shared__ float sred[64][9];       // pad to 9: breaks 16-way read conflict
    __shared__ float s_lds[64];
    __shared__ float la_s[66];          // last_attn halo [t0-1 .. t0+64]

    int tid = threadIdx.x;
    int blk = blockIdx.x;
    int b = blk >> 6;
    int t0 = (blk & 63) << 6;

    int lane = tid & 63, ng = tid >> 6;
    int quad = lane >> 4, lm = lane & 15;

    // B prologue: issue kb=0,1 before staging so they fly during the A stage
    const _Float16* bp = Bpack + (size_t)(ng * 2) * 512 + lane * 8;
    half8 breg[4][2];
    #pragma unroll
    for (int kb = 0; kb < 2; ++kb)
        #pragma unroll
        for (int nt = 0; nt < 2; ++nt)
            breg[kb][nt] = *(const half8*)(bp + kb * 16384 + nt * 512);
    bp += 2 * 16384;

    // epilogue scalars: issue now, consumed after the K-loop
    float qvv[2], c0v[2], c1v[2], c2v[2], wvv[2];
    #pragma unroll
    for (int nt = 0; nt < 2; ++nt) {
        int o = ng * 32 + nt * 16 + lm;
        qvv[nt] = qb[b * HH + o];
        c0v[nt] = conv_w[o * 3 + 0];
        c1v[nt] = conv_w[o * 3 + 1];
        c2v[nt] = conv_w[o * 3 + 2];
        wvv[nt] = w_score[o];
    }

    // last_attn halo -> LDS
    if (tid < 66) {
        int tg = t0 - 1 + tid;
        la_s[tid] = (tg >= 0 && tg < TT) ? last_attn[b * TT + tg] : 0.f;
    }

    // ---- stage A: 64 rows x 512 f32 -> f16 LDS, xor-chunk swizzle ----
    {
        int row = tid >> 3, cc = tid & 7;
        const float4* pA = (const float4*)(value + ((size_t)(b * TT + t0 + row)) * HH);
        #pragma unroll
        for (int u = 0; u < 8; ++u) {
            int c_log = cc + u * 8;
            float4 v0 = pA[2 * c_log], v1 = pA[2 * c_log + 1];
            int cph = c_log ^ (row & 7);
            half8 h = { (_Float16)v0.x, (_Float16)v0.y, (_Float16)v0.z, (_Float16)v0.w,
                        (_Float16)v1.x, (_Float16)v1.y, (_Float16)v1.z, (_Float16)v1.w };
            *(half8*)(As + row * 512 + cph * 8) = h;
        }
    }

    f32x4 acc[4][2];
    #pragma unroll
    for (int mt = 0; mt < 4; ++mt)
        #pragma unroll
        for (int nt = 0; nt < 2; ++nt) { f32x4 z = {0.f,0.f,0.f,0.f}; acc[mt][nt] = z; }

    __syncthreads();

    #pragma unroll 4
    for (int kb = 0; kb < 16; ++kb) {
        if (kb < 14) {
            #pragma unroll
            for (int nt = 0; nt < 2; ++nt)
                breg[(kb + 2) & 3][nt] = *(const half8*)(bp + nt * 512);
            bp += 16384;
        }
        #pragma unroll
        for (int mt = 0; mt < 4; ++mt) {
            int tr = mt * 16 + lm;
            int cph = ((kb << 2) + quad) ^ (tr & 7);
            half8 a = *(const half8*)(As + tr * 512 + cph * 8);
            #pragma unroll
            for (int nt = 0; nt < 2; ++nt)
                acc[mt][nt] = __builtin_amdgcn_mfma_f32_16x16x32_f16(a, breg[kb & 3][nt], acc[mt][nt], 0, 0, 0);
        }
    }

    // ---- epilogue: conv + tanh + w_score dot ----
    #pragma unroll
    for (int mt = 0; mt < 4; ++mt) {
        float rsj[4];
        #pragma unroll
        for (int j = 0; j < 4; ++j) {
            int tl = mt * 16 + quad * 4 + j;          // local row 0..63
            float lam = la_s[tl];
            float la0 = la_s[tl + 1];
            float lap = la_s[tl + 2];
            float r = 0.f;
            #pragma unroll
            for (int nt = 0; nt < 2; ++nt) {
                float act = acc[mt][nt][j] + qvv[nt]
                          + c0v[nt] * lam + c1v[nt] * la0 + c2v[nt] * lap;
                act = fminf(15.f, fmaxf(-15.f, act));
                float e2 = __expf(2.f * act);
                r += (1.f - 2.f * fast_rcp(e2 + 1.f)) * wvv[nt];
            }
            #pragma unroll
            for (int off = 1; off < 16; off <<= 1) r += __shfl_xor(r, off, 64);
            rsj[j] = r;
        }
        if (lm == 0)
            #pragma unroll
            for (int j = 0; j < 4; ++j)
                sred[mt * 16 + quad * 4 + j][ng] = rsj[j];
    }
    __syncthreads();

    if (tid < 64) {
        float sc = b_score[0];
        #pragma unroll
        for (int k = 0; k < 8; ++k) sc += sred[tid][k];
        float s = fast_rcp(1.f + __expf(-sc));
        s_lds[tid] = s;
        sbuf[b * TT + t0 + tid] = s;
        float tot = s;
        #pragma unroll
        for (int off = 1; off < 64; off <<= 1) tot += __shfl_xor(tot, off, 64);
        if (tid == 0) atomicAdd(&ssum[b], tot);
    }
    __syncthreads();

    // ---- context partial from resident f16 tile: one column per thread ----
    {
        int h = tid;
        int cl = h >> 3, j = h & 7;
        float a = 0.f;
        #pragma unroll 8
        for (int t2 = 0; t2 < 64; ++t2) {
            int cph = cl ^ (t2 & 7);
            a += s_lds[t2] * (float)As[t2 * 512 + cph * 8 + j];
        }
        atomicAdd(&ctx[b * HH + h], a);
    }
}

// ---------------- finalize: out = [ctx/ssum, query] ++ attn = s/ssum -----------
__global__ void finalize_kernel(const float* __restrict__ query,
                                const float* __restrict__ ctx,
                                const float* __restrict__ sbuf,
                                const float* __restrict__ ssum,
                                float* __restrict__ out) {
    int idx = blockIdx.x * 256 + threadIdx.x;
    if (idx < BB * 2 * HH) {
        int b = idx >> 10, c = idx & 1023;
        float v;
        if (c < HH) v = ctx[b * HH + c] / ssum[b];
        else        v = query[b * HH + (c - HH)];
        out[idx] = v;
    } else {
        int j = idx - BB * 2 * HH;
        int b = j >> 12, t = j & 4095;
        out[idx] = sbuf[b * TT + t] / ssum[b];
    }
}

extern "C" void kernel_launch(void* const* d_in, const int* in_sizes, int n_in,
                              void* d_out, int out_size, void* d_ws, size_t ws_size,
                              hipStream_t stream) {
    const float* query     = (const float*)d_in[0];
    const float* value     = (const float*)d_in[1];
    const float* last_attn = (const float*)d_in[2];
    const float* conv_w    = (const float*)d_in[3];
    const float* conv_b    = (const float*)d_in[4];
    const float* Wq        = (const float*)d_in[5];
    const float* Wv        = (const float*)d_in[6];
    const float* bias      = (const float*)d_in[7];
    const float* w_score   = (const float*)d_in[8];
    const float* b_score   = (const float*)d_in[9];

    char* ws = (char*)d_ws;
    _Float16* Bpack = (_Float16*)ws;           // 524288 B
    float* qb     = (float*)(ws + 524288);     // 32768 B
    float* sbuf   = (float*)(ws + 557056);     // 262144 B
    float* ssum   = (float*)(ws + 819200);     // 64 B
    float* ctx    = (float*)(ws + 819264);     // 32768 B
    float* out    = (float*)d_out;

    static bool attr_set = false;
    if (!attr_set) {
        hipFuncSetAttribute((const void*)gemm_fused_kernel,
                            hipFuncAttributeMaxDynamicSharedMemorySize, 65536);
        attr_set = true;
    }

    prep_kernel<<<193, 256, 0, stream>>>(query, conv_b, Wq, Wv, bias, Bpack, qb, ssum, ctx);
    gemm_fused_kernel<<<1024, 512, 65536, stream>>>(value, last_attn, conv_w, w_score,
                                                    b_score, Bpack, qb, sbuf, ssum, ctx);
    finalize_kernel<<<320, 256, 0, stream>>>(query, ctx, sbuf, ssum, out);
}